// Round 3
// baseline (5543.693 us; speedup 1.0000x reference)
//
#include <hip/hip_runtime.h>

#define BH 64
#define KLEN 4096
#define QLEN 512
#define DIM 128
#define RP 32
#define NSWEEP 6

// ---------------- Gram partials: Gpart[c] = Kc^T Kc over chunk c, Spart[c] = col sums ----------------
__global__ __launch_bounds__(256) void gram_kernel(const float* __restrict__ K,
                                                   float* __restrict__ Gpart,
                                                   float* __restrict__ Spart) {
    int bh = blockIdx.y, chunk = blockIdx.x;                  // 4 chunks of 1024 rows
    const float* Kb = K + ((size_t)bh * KLEN + (size_t)chunk * 1024) * DIM;
    __shared__ float Kt[32][129];                             // +1 pad: conflict-free column sums
    int t = threadIdx.x;
    int ty = t >> 4, tx = t & 15;                             // 16x16 threads, each 8x8 tile of C
    float acc[8][8];
#pragma unroll
    for (int i = 0; i < 8; i++)
#pragma unroll
        for (int j = 0; j < 8; j++) acc[i][j] = 0.f;
    float s_acc = 0.f;
    for (int tile = 0; tile < 32; tile++) {
        __syncthreads();
        for (int k = 0; k < 16; k++) {                        // load 32x128 coalesced
            int idx = t + k * 256;
            Kt[idx >> 7][idx & 127] = Kb[tile * 32 * DIM + idx];
        }
        __syncthreads();
#pragma unroll 4
        for (int r = 0; r < 32; r++) {
            float a_[8], b_[8];
#pragma unroll
            for (int i = 0; i < 8; i++) a_[i] = Kt[r][ty * 8 + i];
#pragma unroll
            for (int j = 0; j < 8; j++) b_[j] = Kt[r][tx * 8 + j];
#pragma unroll
            for (int i = 0; i < 8; i++)
#pragma unroll
                for (int j = 0; j < 8; j++) acc[i][j] += a_[i] * b_[j];
        }
        if (t < 128) { float ss = 0.f; for (int r = 0; r < 32; r++) ss += Kt[r][t]; s_acc += ss; }
    }
    float* Gb = Gpart + ((size_t)chunk * BH + bh) * DIM * DIM;
#pragma unroll
    for (int i = 0; i < 8; i++)
#pragma unroll
        for (int j = 0; j < 8; j++) Gb[(ty * 8 + i) * DIM + tx * 8 + j] = acc[i][j];
    if (t < 128) Spart[((size_t)chunk * BH + bh) * DIM + t] = s_acc;
}

// ---------------- Jacobi eigensolver: replicated full-C / partitioned Vm ----------------
// Grid (4 slices, BH). Each block holds a FULL C (structured, conflict-free round-1 update
// pattern: lane i -> consecutive rows pi, bank=(pi+pj)&31 -> 2-way) and redundantly computes
// the sandwich + angles (bitwise identical across the 4 replicas -> identical rank select).
// Each block owns a 32-row slice of Vm / Bout. Arithmetic (p,q) pairing, float2 angles.
__device__ __forceinline__ void pair_pq(int r, int x, int& p, int& q) {
    if (x == 0) { p = 127; q = r; }
    else {
        int a = r + x;       a -= (a >= 127) ? 127 : 0;
        int b = r + 127 - x; b -= (b >= 127) ? 127 : 0;
        p = a; q = b;
    }
}

__global__ __launch_bounds__(1024) void jacobi_kernel(const float* __restrict__ Gpart,
                                                      const float* __restrict__ Spart,
                                                      float* __restrict__ Bout) {
    __shared__ float C[128][129];    // full matrix, +1 pad
    __shared__ float Vm[32][129];    // this block's 32-row slice of eigenvectors
    __shared__ float2 csA[2][64];    // (c,s) per pair, double-buffered
    __shared__ float diag[128];      // summed-S at load, eigenvalues at end
    int slice = blockIdx.x, bh = blockIdx.y, t = threadIdx.x;
    const size_t gslab = (size_t)BH * DIM * DIM;
    const float* Gb = Gpart + (size_t)bh * DIM * DIM;

    if (t < 128) {
        float s = 0.f;
#pragma unroll
        for (int c = 0; c < 4; c++) s += Spart[((size_t)c * BH + bh) * DIM + t];
        diag[t] = s;
    }
    __syncthreads();
    for (int k = 0; k < 16; k++) {
        int idx = t + k * 1024;
        int i = idx >> 7, j = idx & 127;
        float g = Gb[idx] + Gb[gslab + idx] + Gb[2 * gslab + idx] + Gb[3 * gslab + idx];
        C[i][j] = g - diag[i] * diag[j] * (1.0f / 4096.0f);
    }
    for (int k = 0; k < 4; k++) {          // Vm slice = identity rows [32*slice, 32*slice+32)
        int idx = t + k * 1024;
        int kk = idx >> 7, j = idx & 127;
        Vm[kk][j] = (32 * slice + kk == j) ? 1.0f : 0.0f;
    }
    __syncthreads();
    // prologue: angles for round 0
    if (t < 64) {
        int p, q;
        pair_pq(0, t, p, q);
        float app = C[p][p], aqq = C[q][q], apq = C[p][q];
        float c = 1.0f, s = 0.0f;
        if (apq != 0.0f) {
            float tau = (aqq - app) / (2.0f * apq);
            float root = sqrtf(1.0f + tau * tau);
            float tt = (tau >= 0.0f) ? 1.0f / (tau + root) : 1.0f / (tau - root);
            c = 1.0f / sqrtf(1.0f + tt * tt);
            s = tt * c;
        }
        csA[0][t] = make_float2(c, s);
    }
    __syncthreads();

    const int NR = NSWEEP * 127;
    int r = 0;                                   // r = sr % 127
    for (int sr = 0; sr < NR; sr++) {
        int cur = sr & 1, nxt = cur ^ 1;
        // ---- phase A: full-matrix sandwich; 4096 fused 2x2 tasks; structured banks ----
        {
            int i = t & 63, jb = (t >> 6) << 2;  // jb wave-uniform
            int pi, qi; pair_pq(r, i, pi, qi);
            float2 csi = csA[cur][i];
#pragma unroll
            for (int jj = 0; jj < 4; jj++) {
                int j = jb + jj;
                int pj, qj; pair_pq(r, j, pj, qj);
                float2 csj = csA[cur][j];
                float a = C[pi][pj], b = C[pi][qj], d = C[qi][pj], e = C[qi][qj];
                float a1 = csj.x * a - csj.y * b, b1 = csj.y * a + csj.x * b;
                float d1 = csj.x * d - csj.y * e, e1 = csj.y * d + csj.x * e;
                C[pi][pj] = csi.x * a1 - csi.y * d1;
                C[qi][pj] = csi.y * a1 + csi.x * d1;
                C[pi][qj] = csi.x * b1 - csi.y * e1;
                C[qi][qj] = csi.y * b1 + csi.x * e1;
            }
        }
        __syncthreads();
        // ---- phase B: Vm slice rotations (waves 1..15) || next-round angles (wave 0) ----
        if (t < 64) {
            if (sr + 1 < NR) {
                int r2 = (r + 1 == 127) ? 0 : r + 1;
                int p, q;
                pair_pq(r2, t, p, q);
                float app = C[p][p], aqq = C[q][q], apq = C[p][q];
                float c = 1.0f, s = 0.0f;
                if (apq != 0.0f) {
                    float tau = (aqq - app) / (2.0f * apq);
                    float root = sqrtf(1.0f + tau * tau);
                    float tt = (tau >= 0.0f) ? 1.0f / (tau + root) : 1.0f / (tau - root);
                    c = 1.0f / sqrtf(1.0f + tt * tt);
                    s = tt * c;
                }
                csA[nxt][t] = make_float2(c, s);
            }
        } else {
            int tt = t - 64;
            for (int tau = tt; tau < 2048; tau += 960) {   // 32 rows x 64 pairs
                int x = tau & 63, k = tau >> 6;
                int pj, qj; pair_pq(r, x, pj, qj);
                float2 cs = csA[cur][x];
                float u = Vm[k][pj], v = Vm[k][qj];
                Vm[k][pj] = cs.x * u - cs.y * v;
                Vm[k][qj] = cs.y * u + cs.x * v;
            }
        }
        __syncthreads();
        r = (r + 1 == 127) ? 0 : r + 1;
    }

    if (t < 128) diag[t] = C[t][t];
    __syncthreads();
    if (t < 128) {   // rank-select top-32; identical across replicas (bitwise-same C)
        float dt = diag[t];
        int rank = 0;
        for (int j = 0; j < 128; j++) {
            float dj = diag[j];
            rank += (dj > dt) || (dj == dt && j < t);
        }
        if (rank < RP) {
            float* Bb = Bout + (size_t)bh * DIM * RP;
            for (int k = 0; k < 32; k++) Bb[(size_t)(32 * slice + k) * RP + rank] = Vm[k][t];
        }
    }
}

// ---------------- projection: Y[row][r] = sum_k X[row][k] * B[k][r] ----------------
__global__ __launch_bounds__(256) void proj_kernel(const float* __restrict__ X,
                                                   const float* __restrict__ Bmat,
                                                   float* __restrict__ Y, int nrows) {
    int bh = blockIdx.y, rb = blockIdx.x;
    __shared__ float Bl[128][33];
    __shared__ float Xt[64][129];
    int t = threadIdx.x;
    for (int k = 0; k < 16; k++) {
        int idx = t + k * 256;
        Bl[idx >> 5][idx & 31] = Bmat[(size_t)bh * DIM * RP + idx];
    }
    const float* Xb = X + ((size_t)bh * nrows + (size_t)rb * 64) * DIM;
    for (int k = 0; k < 32; k++) {
        int idx = t + k * 256;
        Xt[idx >> 7][idx & 127] = Xb[idx];
    }
    __syncthreads();
    int row = t >> 2, rg = (t & 3) * 8;
    float acc[8] = {0.f, 0.f, 0.f, 0.f, 0.f, 0.f, 0.f, 0.f};
    for (int k = 0; k < 128; k++) {
        float xv = Xt[row][k];
#pragma unroll
        for (int rr = 0; rr < 8; rr++) acc[rr] += xv * Bl[k][rg + rr];
    }
    float* Yb = Y + ((size_t)bh * nrows + (size_t)rb * 64) * RP + row * RP + rg;
#pragma unroll
    for (int rr = 0; rr < 8; rr++) Yb[rr] = acc[rr];
}

// ---------------- fused flash-style attention: softmax(Qp Kp^T * scale) @ V ----------------
// 2 q-rows per thread (each Kpl/Vt LDS read feeds 2x the FMAs); weights exchanged across
// the 4 g-lanes via __shfl_xor ring (no Sl buffer: LDS 52 KB). 128-thread blocks, grid (8,BH).
__global__ __launch_bounds__(128, 2) void attn_kernel(const float* __restrict__ Qp,
                                                      const float* __restrict__ Kp,
                                                      const float* __restrict__ Vg,
                                                      float* __restrict__ Out) {
    const float SCALE = 0.1767766953f;  // 1/sqrt(32)
    int qt = blockIdx.x, bh = blockIdx.y;
    __shared__ float Kpl[128][36];      // rows of 32 floats, stride 36
    __shared__ float Vt[64][132];       // half V tile, stride 132
    int t = threadIdx.x;
    int q = t >> 2, g = t & 3;          // q in [0,32); thread owns rows q and q+32 of the 64-row tile
    float qreg0[32], qreg1[32];
    {
        const float4* Qb0 = (const float4*)(Qp + ((size_t)bh * QLEN + (size_t)qt * 64 + q) * RP);
        const float4* Qb1 = (const float4*)(Qp + ((size_t)bh * QLEN + (size_t)qt * 64 + 32 + q) * RP);
#pragma unroll
        for (int r4 = 0; r4 < 8; r4++) {
            float4 a = Qb0[r4], b = Qb1[r4];
            qreg0[r4*4+0] = a.x; qreg0[r4*4+1] = a.y; qreg0[r4*4+2] = a.z; qreg0[r4*4+3] = a.w;
            qreg1[r4*4+0] = b.x; qreg1[r4*4+1] = b.y; qreg1[r4*4+2] = b.z; qreg1[r4*4+3] = b.w;
        }
    }
    float acc0[32], acc1[32];
#pragma unroll
    for (int i = 0; i < 32; i++) { acc0[i] = 0.f; acc1[i] = 0.f; }
    float m0 = -INFINITY, l0 = 0.f, m1 = -INFINITY, l1 = 0.f;

    for (int kt = 0; kt < 32; kt++) {
        __syncthreads();
        const float4* Kpb = (const float4*)(Kp + ((size_t)bh * KLEN + (size_t)kt * 128) * RP);
#pragma unroll
        for (int k = 0; k < 8; k++) {
            int idx4 = t + k * 128;
            *(float4*)&Kpl[idx4 >> 3][(idx4 & 7) * 4] = Kpb[idx4];
        }
        __syncthreads();
        // ---- scores: thread (q,g) owns kv j = jj*4+g; one Kpl read feeds both q rows ----
        float s0[32], s1[32];
#pragma unroll
        for (int jj = 0; jj < 32; jj++) {
            int j = jj * 4 + g;
            float a0 = 0.f, a1 = 0.f;
#pragma unroll
            for (int r4 = 0; r4 < 8; r4++) {
                float4 kv = *(const float4*)&Kpl[j][r4 * 4];
                a0 += qreg0[r4*4+0]*kv.x + qreg0[r4*4+1]*kv.y + qreg0[r4*4+2]*kv.z + qreg0[r4*4+3]*kv.w;
                a1 += qreg1[r4*4+0]*kv.x + qreg1[r4*4+1]*kv.y + qreg1[r4*4+2]*kv.z + qreg1[r4*4+3]*kv.w;
            }
            s0[jj] = a0 * SCALE;
            s1[jj] = a1 * SCALE;
        }
        // ---- online softmax, register + 4-lane shuffle reduce ----
        float mx0 = s0[0], mx1 = s1[0];
#pragma unroll
        for (int jj = 1; jj < 32; jj++) { mx0 = fmaxf(mx0, s0[jj]); mx1 = fmaxf(mx1, s1[jj]); }
        mx0 = fmaxf(mx0, __shfl_xor(mx0, 1)); mx0 = fmaxf(mx0, __shfl_xor(mx0, 2));
        mx1 = fmaxf(mx1, __shfl_xor(mx1, 1)); mx1 = fmaxf(mx1, __shfl_xor(mx1, 2));
        float mn0 = fmaxf(m0, mx0), mn1 = fmaxf(m1, mx1);
        float al0 = __expf(m0 - mn0), al1 = __expf(m1 - mn1);   // first tile: exp(-inf)=0
        float ps0 = 0.f, ps1 = 0.f;
#pragma unroll
        for (int jj = 0; jj < 32; jj++) {
            float w0 = __expf(s0[jj] - mn0); s0[jj] = w0; ps0 += w0;
            float w1 = __expf(s1[jj] - mn1); s1[jj] = w1; ps1 += w1;
        }
        ps0 += __shfl_xor(ps0, 1); ps0 += __shfl_xor(ps0, 2);
        ps1 += __shfl_xor(ps1, 1); ps1 += __shfl_xor(ps1, 2);
        l0 = l0 * al0 + ps0; m0 = mn0;
        l1 = l1 * al1 + ps1; m1 = mn1;
#pragma unroll
        for (int i = 0; i < 32; i++) { acc0[i] *= al0; acc1[i] *= al1; }
        // ---- PV: V in 2 half-tiles; weights shuffled across the 4 g-lanes (no Sl) ----
#pragma unroll
        for (int ss = 0; ss < 2; ss++) {
            __syncthreads();
            const float4* Vb = (const float4*)(Vg + ((size_t)bh * KLEN + (size_t)kt * 128 + (size_t)ss * 64) * DIM);
#pragma unroll
            for (int k = 0; k < 16; k++) {
                int idx4 = t + k * 128;
                *(float4*)&Vt[idx4 >> 5][(idx4 & 31) * 4] = Vb[idx4];
            }
            __syncthreads();
#pragma unroll
            for (int m = 0; m < 4; m++) {
                int gs = g ^ m;
#pragma unroll
                for (int jj16 = 0; jj16 < 16; jj16++) {
                    int jj = ss * 16 + jj16;                 // static index into s0/s1
                    float w0 = m ? __shfl_xor(s0[jj], m) : s0[jj];
                    float w1 = m ? __shfl_xor(s1[jj], m) : s1[jj];
                    int jl = jj16 * 4 + gs;                  // local V row in [0,64)
#pragma unroll
                    for (int i4 = 0; i4 < 8; i4++) {
                        float4 vv = *(const float4*)&Vt[jl][i4 * 16 + g * 4];
                        acc0[i4*4+0] += w0 * vv.x; acc0[i4*4+1] += w0 * vv.y;
                        acc0[i4*4+2] += w0 * vv.z; acc0[i4*4+3] += w0 * vv.w;
                        acc1[i4*4+0] += w1 * vv.x; acc1[i4*4+1] += w1 * vv.y;
                        acc1[i4*4+2] += w1 * vv.z; acc1[i4*4+3] += w1 * vv.w;
                    }
                }
            }
        }
    }
    float li0 = 1.0f / l0, li1 = 1.0f / l1;
    float* Ob0 = Out + ((size_t)bh * QLEN + (size_t)qt * 64 + q) * DIM;
    float* Ob1 = Out + ((size_t)bh * QLEN + (size_t)qt * 64 + 32 + q) * DIM;
#pragma unroll
    for (int i4 = 0; i4 < 8; i4++) {
        float4 o0, o1;
        o0.x = acc0[i4*4+0]*li0; o0.y = acc0[i4*4+1]*li0; o0.z = acc0[i4*4+2]*li0; o0.w = acc0[i4*4+3]*li0;
        o1.x = acc1[i4*4+0]*li1; o1.y = acc1[i4*4+1]*li1; o1.z = acc1[i4*4+2]*li1; o1.w = acc1[i4*4+3]*li1;
        *(float4*)&Ob0[i4 * 16 + g * 4] = o0;
        *(float4*)&Ob1[i4 * 16 + g * 4] = o1;
    }
}

extern "C" void kernel_launch(void* const* d_in, const int* in_sizes, int n_in,
                              void* d_out, int out_size, void* d_ws, size_t ws_size,
                              hipStream_t stream) {
    const float* Q = (const float*)d_in[0];
    const float* K = (const float*)d_in[1];
    const float* V = (const float*)d_in[2];
    float* out = (float*)d_out;
    float* ws = (float*)d_ws;
    float* G  = ws;                                   // unused (layout stability)
    float* S  = G + (size_t)BH * DIM * DIM;
    float* Bm = S + BH * DIM;
    float* Kp = Bm + (size_t)BH * DIM * RP;
    float* Qp = Kp + (size_t)BH * KLEN * RP;
    float* Gpart = Kp;                                // 4 * BH * 128 * 128 floats (pre-proj scratch)
    float* Spart = Gpart + (size_t)4 * BH * DIM * DIM;

    gram_kernel<<<dim3(4, BH), 256, 0, stream>>>(K, Gpart, Spart);
    jacobi_kernel<<<dim3(4, BH), 1024, 0, stream>>>(Gpart, Spart, Bm);
    proj_kernel<<<dim3(KLEN / 64, BH), 256, 0, stream>>>(K, Bm, Kp, KLEN);
    proj_kernel<<<dim3(QLEN / 64, BH), 256, 0, stream>>>(Q, Bm, Qp, QLEN);
    attn_kernel<<<dim3(QLEN / 64, BH), 128, 0, stream>>>(Qp, Kp, V, out);
}

// Round 4
// 2783.856 us; speedup vs baseline: 1.9914x; 1.9914x over previous
//
#include <hip/hip_runtime.h>

#define BH 64
#define KLEN 4096
#define QLEN 512
#define DIM 128
#define RP 32
#define NSWEEP 6

// ---------------- Gram partials: Gpart[c] = Kc^T Kc over chunk c, Spart[c] = col sums ----------------
__global__ __launch_bounds__(256) void gram_kernel(const float* __restrict__ K,
                                                   float* __restrict__ Gpart,
                                                   float* __restrict__ Spart) {
    int bh = blockIdx.y, chunk = blockIdx.x;                  // 4 chunks of 1024 rows
    const float* Kb = K + ((size_t)bh * KLEN + (size_t)chunk * 1024) * DIM;
    __shared__ float Kt[32][129];                             // +1 pad: conflict-free column sums
    int t = threadIdx.x;
    int ty = t >> 4, tx = t & 15;                             // 16x16 threads, each 8x8 tile of C
    float acc[8][8];
#pragma unroll
    for (int i = 0; i < 8; i++)
#pragma unroll
        for (int j = 0; j < 8; j++) acc[i][j] = 0.f;
    float s_acc = 0.f;
    for (int tile = 0; tile < 32; tile++) {
        __syncthreads();
        for (int k = 0; k < 16; k++) {                        // load 32x128 coalesced
            int idx = t + k * 256;
            Kt[idx >> 7][idx & 127] = Kb[tile * 32 * DIM + idx];
        }
        __syncthreads();
#pragma unroll 4
        for (int r = 0; r < 32; r++) {
            float a_[8], b_[8];
#pragma unroll
            for (int i = 0; i < 8; i++) a_[i] = Kt[r][ty * 8 + i];
#pragma unroll
            for (int j = 0; j < 8; j++) b_[j] = Kt[r][tx * 8 + j];
#pragma unroll
            for (int i = 0; i < 8; i++)
#pragma unroll
                for (int j = 0; j < 8; j++) acc[i][j] += a_[i] * b_[j];
        }
        if (t < 128) { float ss = 0.f; for (int r = 0; r < 32; r++) ss += Kt[r][t]; s_acc += ss; }
    }
    float* Gb = Gpart + ((size_t)chunk * BH + bh) * DIM * DIM;
#pragma unroll
    for (int i = 0; i < 8; i++)
#pragma unroll
        for (int j = 0; j < 8; j++) Gb[(ty * 8 + i) * DIM + tx * 8 + j] = acc[i][j];
    if (t < 128) Spart[((size_t)chunk * BH + bh) * DIM + t] = s_acc;
}

// ---------------- Jacobi eigensolver: replicated full-C / partitioned Vm ----------------
__device__ __forceinline__ void pair_pq(int r, int x, int& p, int& q) {
    if (x == 0) { p = 127; q = r; }
    else {
        int a = r + x;       a -= (a >= 127) ? 127 : 0;
        int b = r + 127 - x; b -= (b >= 127) ? 127 : 0;
        p = a; q = b;
    }
}

__global__ __launch_bounds__(1024) void jacobi_kernel(const float* __restrict__ Gpart,
                                                      const float* __restrict__ Spart,
                                                      float* __restrict__ Bout) {
    __shared__ float C[128][129];    // full matrix, +1 pad
    __shared__ float Vm[32][129];    // this block's 32-row slice of eigenvectors
    __shared__ float2 csA[2][64];    // (c,s) per pair, double-buffered
    __shared__ float diag[128];      // summed-S at load, eigenvalues at end
    int slice = blockIdx.x, bh = blockIdx.y, t = threadIdx.x;
    const size_t gslab = (size_t)BH * DIM * DIM;
    const float* Gb = Gpart + (size_t)bh * DIM * DIM;

    if (t < 128) {
        float s = 0.f;
#pragma unroll
        for (int c = 0; c < 4; c++) s += Spart[((size_t)c * BH + bh) * DIM + t];
        diag[t] = s;
    }
    __syncthreads();
    for (int k = 0; k < 16; k++) {
        int idx = t + k * 1024;
        int i = idx >> 7, j = idx & 127;
        float g = Gb[idx] + Gb[gslab + idx] + Gb[2 * gslab + idx] + Gb[3 * gslab + idx];
        C[i][j] = g - diag[i] * diag[j] * (1.0f / 4096.0f);
    }
    for (int k = 0; k < 4; k++) {          // Vm slice = identity rows [32*slice, 32*slice+32)
        int idx = t + k * 1024;
        int kk = idx >> 7, j = idx & 127;
        Vm[kk][j] = (32 * slice + kk == j) ? 1.0f : 0.0f;
    }
    __syncthreads();
    // prologue: angles for round 0
    if (t < 64) {
        int p, q;
        pair_pq(0, t, p, q);
        float app = C[p][p], aqq = C[q][q], apq = C[p][q];
        float c = 1.0f, s = 0.0f;
        if (apq != 0.0f) {
            float tau = (aqq - app) / (2.0f * apq);
            float root = sqrtf(1.0f + tau * tau);
            float tt = (tau >= 0.0f) ? 1.0f / (tau + root) : 1.0f / (tau - root);
            c = 1.0f / sqrtf(1.0f + tt * tt);
            s = tt * c;
        }
        csA[0][t] = make_float2(c, s);
    }
    __syncthreads();

    const int NR = NSWEEP * 127;
    int r = 0;                                   // r = sr % 127
    for (int sr = 0; sr < NR; sr++) {
        int cur = sr & 1, nxt = cur ^ 1;
        // ---- phase A: full-matrix sandwich; 4096 fused 2x2 tasks; structured banks ----
        {
            int i = t & 63, jb = (t >> 6) << 2;  // jb wave-uniform
            int pi, qi; pair_pq(r, i, pi, qi);
            float2 csi = csA[cur][i];
#pragma unroll
            for (int jj = 0; jj < 4; jj++) {
                int j = jb + jj;
                int pj, qj; pair_pq(r, j, pj, qj);
                float2 csj = csA[cur][j];
                float a = C[pi][pj], b = C[pi][qj], d = C[qi][pj], e = C[qi][qj];
                float a1 = csj.x * a - csj.y * b, b1 = csj.y * a + csj.x * b;
                float d1 = csj.x * d - csj.y * e, e1 = csj.y * d + csj.x * e;
                C[pi][pj] = csi.x * a1 - csi.y * d1;
                C[qi][pj] = csi.y * a1 + csi.x * d1;
                C[pi][qj] = csi.x * b1 - csi.y * e1;
                C[qi][qj] = csi.y * b1 + csi.x * e1;
            }
        }
        __syncthreads();
        // ---- phase B: Vm slice rotations (waves 1..15) || next-round angles (wave 0) ----
        if (t < 64) {
            if (sr + 1 < NR) {
                int r2 = (r + 1 == 127) ? 0 : r + 1;
                int p, q;
                pair_pq(r2, t, p, q);
                float app = C[p][p], aqq = C[q][q], apq = C[p][q];
                float c = 1.0f, s = 0.0f;
                if (apq != 0.0f) {
                    float tau = (aqq - app) / (2.0f * apq);
                    float root = sqrtf(1.0f + tau * tau);
                    float tt = (tau >= 0.0f) ? 1.0f / (tau + root) : 1.0f / (tau - root);
                    c = 1.0f / sqrtf(1.0f + tt * tt);
                    s = tt * c;
                }
                csA[nxt][t] = make_float2(c, s);
            }
        } else {
            int tt = t - 64;
            for (int tau = tt; tau < 2048; tau += 960) {   // 32 rows x 64 pairs
                int x = tau & 63, k = tau >> 6;
                int pj, qj; pair_pq(r, x, pj, qj);
                float2 cs = csA[cur][x];
                float u = Vm[k][pj], v = Vm[k][qj];
                Vm[k][pj] = cs.x * u - cs.y * v;
                Vm[k][qj] = cs.y * u + cs.x * v;
            }
        }
        __syncthreads();
        r = (r + 1 == 127) ? 0 : r + 1;
    }

    if (t < 128) diag[t] = C[t][t];
    __syncthreads();
    if (t < 128) {   // rank-select top-32; identical across replicas (bitwise-same C)
        float dt = diag[t];
        int rank = 0;
        for (int j = 0; j < 128; j++) {
            float dj = diag[j];
            rank += (dj > dt) || (dj == dt && j < t);
        }
        if (rank < RP) {
            float* Bb = Bout + (size_t)bh * DIM * RP;
            for (int k = 0; k < 32; k++) Bb[(size_t)(32 * slice + k) * RP + rank] = Vm[k][t];
        }
    }
}

// ---------------- projection: Y[row][r] = sum_k X[row][k] * B[k][r] ----------------
__global__ __launch_bounds__(256) void proj_kernel(const float* __restrict__ X,
                                                   const float* __restrict__ Bmat,
                                                   float* __restrict__ Y, int nrows) {
    int bh = blockIdx.y, rb = blockIdx.x;
    __shared__ float Bl[128][33];
    __shared__ float Xt[64][129];
    int t = threadIdx.x;
    for (int k = 0; k < 16; k++) {
        int idx = t + k * 256;
        Bl[idx >> 5][idx & 31] = Bmat[(size_t)bh * DIM * RP + idx];
    }
    const float* Xb = X + ((size_t)bh * nrows + (size_t)rb * 64) * DIM;
    for (int k = 0; k < 32; k++) {
        int idx = t + k * 256;
        Xt[idx >> 7][idx & 127] = Xb[idx];
    }
    __syncthreads();
    int row = t >> 2, rg = (t & 3) * 8;
    float acc[8] = {0.f, 0.f, 0.f, 0.f, 0.f, 0.f, 0.f, 0.f};
    for (int k = 0; k < 128; k++) {
        float xv = Xt[row][k];
#pragma unroll
        for (int rr = 0; rr < 8; rr++) acc[rr] += xv * Bl[k][rg + rr];
    }
    float* Yb = Y + ((size_t)bh * nrows + (size_t)rb * 64) * RP + row * RP + rg;
#pragma unroll
    for (int rr = 0; rr < 8; rr++) Yb[rr] = acc[rr];
}

// ---------------- fused flash-style attention: softmax(Qp Kp^T * scale) @ V ----------------
// nq=2, register-safe: 256 threads, 64-row q-tile, 8 lanes per query (q=t>>3, g=t&7).
// Thread owns rows {q, q+32}, 16 kv for scores (s0/s1[16]), 16 dims (4 float4 chunks c*8+g).
// Weights exchanged via Sl[64][132] LDS buffer UNION'd with Kpl (disjoint lifetimes).
// Every hot LDS access conflict-free: Kpl b128 quad=(g+r4)&7, Vt b128 quad=(jl+g)&7,
// Sl reads 8 banks x 8-way broadcast. LDS total 50688 B.
__global__ __launch_bounds__(256, 2) void attn_kernel(const float* __restrict__ Qp,
                                                      const float* __restrict__ Kp,
                                                      const float* __restrict__ Vg,
                                                      float* __restrict__ Out) {
    const float SCALE = 0.1767766953f;  // 1/sqrt(32)
    int qt = blockIdx.x, bh = blockIdx.y;
    __shared__ float ldsA[8448];        // union: Kpl[128][36] (18432B) | Sl[64][132] (33792B)
    __shared__ float Vt[32][132];       // quarter V tile (16896B)
    float (*Kpl)[36]  = (float(*)[36])ldsA;
    float (*Sl)[132]  = (float(*)[132])ldsA;
    int t = threadIdx.x;
    int q = t >> 3, g = t & 7;          // q in [0,32); rows q and q+32 of the 64-row tile
    float qreg0[32], qreg1[32];
    {
        const float4* Qb0 = (const float4*)(Qp + ((size_t)bh * QLEN + (size_t)qt * 64 + q) * RP);
        const float4* Qb1 = (const float4*)(Qp + ((size_t)bh * QLEN + (size_t)qt * 64 + 32 + q) * RP);
#pragma unroll
        for (int r4 = 0; r4 < 8; r4++) {
            float4 a = Qb0[r4], b = Qb1[r4];
            qreg0[r4*4+0] = a.x; qreg0[r4*4+1] = a.y; qreg0[r4*4+2] = a.z; qreg0[r4*4+3] = a.w;
            qreg1[r4*4+0] = b.x; qreg1[r4*4+1] = b.y; qreg1[r4*4+2] = b.z; qreg1[r4*4+3] = b.w;
        }
    }
    float acc0[16], acc1[16];           // dims d = (c*8+g)*4 + e, c in [0,4)
#pragma unroll
    for (int i = 0; i < 16; i++) { acc0[i] = 0.f; acc1[i] = 0.f; }
    float m0 = -INFINITY, l0 = 0.f, m1 = -INFINITY, l1 = 0.f;

    for (int kt = 0; kt < 32; kt++) {
        __syncthreads();                 // prior Sl/Vt readers done
        const float4* Kpb = (const float4*)(Kp + ((size_t)bh * KLEN + (size_t)kt * 128) * RP);
#pragma unroll
        for (int k = 0; k < 4; k++) {    // stage Kp tile 128x32 (1024 float4)
            int idx4 = t + k * 256;
            *(float4*)&Kpl[idx4 >> 3][(idx4 & 7) * 4] = Kpb[idx4];
        }
        __syncthreads();                 // Kpl ready
        // ---- scores: thread owns kv j = jj*8+g; one Kpl read feeds both q rows ----
        float s0[16], s1[16];
#pragma unroll
        for (int jj = 0; jj < 16; jj++) {
            int j = jj * 8 + g;
            float a0 = 0.f, a1 = 0.f;
#pragma unroll
            for (int r4 = 0; r4 < 8; r4++) {
                float4 kv = *(const float4*)&Kpl[j][r4 * 4];
                a0 += qreg0[r4*4+0]*kv.x + qreg0[r4*4+1]*kv.y + qreg0[r4*4+2]*kv.z + qreg0[r4*4+3]*kv.w;
                a1 += qreg1[r4*4+0]*kv.x + qreg1[r4*4+1]*kv.y + qreg1[r4*4+2]*kv.z + qreg1[r4*4+3]*kv.w;
            }
            s0[jj] = a0 * SCALE;
            s1[jj] = a1 * SCALE;
        }
        // ---- online softmax: 16 in-thread + xor-reduce over the 8 g-lanes ----
        float mx0 = s0[0], mx1 = s1[0];
#pragma unroll
        for (int jj = 1; jj < 16; jj++) { mx0 = fmaxf(mx0, s0[jj]); mx1 = fmaxf(mx1, s1[jj]); }
        mx0 = fmaxf(mx0, __shfl_xor(mx0, 1)); mx0 = fmaxf(mx0, __shfl_xor(mx0, 2)); mx0 = fmaxf(mx0, __shfl_xor(mx0, 4));
        mx1 = fmaxf(mx1, __shfl_xor(mx1, 1)); mx1 = fmaxf(mx1, __shfl_xor(mx1, 2)); mx1 = fmaxf(mx1, __shfl_xor(mx1, 4));
        float mn0 = fmaxf(m0, mx0), mn1 = fmaxf(m1, mx1);
        float al0 = __expf(m0 - mn0), al1 = __expf(m1 - mn1);   // first tile: exp(-inf)=0
        float ps0 = 0.f, ps1 = 0.f;
#pragma unroll
        for (int jj = 0; jj < 16; jj++) {
            float w0 = __expf(s0[jj] - mn0); s0[jj] = w0; ps0 += w0;
            float w1 = __expf(s1[jj] - mn1); s1[jj] = w1; ps1 += w1;
        }
        ps0 += __shfl_xor(ps0, 1); ps0 += __shfl_xor(ps0, 2); ps0 += __shfl_xor(ps0, 4);
        ps1 += __shfl_xor(ps1, 1); ps1 += __shfl_xor(ps1, 2); ps1 += __shfl_xor(ps1, 4);
        l0 = l0 * al0 + ps0; m0 = mn0;
        l1 = l1 * al1 + ps1; m1 = mn1;
#pragma unroll
        for (int i = 0; i < 16; i++) { acc0[i] *= al0; acc1[i] *= al1; }
        __syncthreads();                 // Kpl reads done -> safe to overwrite union with Sl
#pragma unroll
        for (int jj = 0; jj < 16; jj++) {
            int j = jj * 8 + g;
            Sl[q][j]      = s0[jj];
            Sl[q + 32][j] = s1[jj];
        }
        // ---- PV: V in 4 quarter-tiles of 32 kv rows; Sl broadcast reads ----
        for (int ss = 0; ss < 4; ss++) {
            if (ss) __syncthreads();     // prior quarter's Vt reads done
            const float4* Vb = (const float4*)(Vg + ((size_t)bh * KLEN + (size_t)kt * 128 + (size_t)ss * 32) * DIM);
#pragma unroll
            for (int k = 0; k < 4; k++) {
                int idx4 = t + k * 256;
                *(float4*)&Vt[idx4 >> 5][(idx4 & 31) * 4] = Vb[idx4];
            }
            __syncthreads();             // Vt (and on ss==0, Sl) ready
            for (int jl = 0; jl < 32; jl++) {
                float w0 = Sl[q][ss * 32 + jl];
                float w1 = Sl[q + 32][ss * 32 + jl];
#pragma unroll
                for (int c = 0; c < 4; c++) {
                    float4 vv = *(const float4*)&Vt[jl][(c * 8 + g) * 4];
                    acc0[c*4+0] += w0 * vv.x; acc0[c*4+1] += w0 * vv.y;
                    acc0[c*4+2] += w0 * vv.z; acc0[c*4+3] += w0 * vv.w;
                    acc1[c*4+0] += w1 * vv.x; acc1[c*4+1] += w1 * vv.y;
                    acc1[c*4+2] += w1 * vv.z; acc1[c*4+3] += w1 * vv.w;
                }
            }
        }
    }
    float li0 = 1.0f / l0, li1 = 1.0f / l1;
    float* Ob0 = Out + ((size_t)bh * QLEN + (size_t)qt * 64 + q) * DIM;
    float* Ob1 = Out + ((size_t)bh * QLEN + (size_t)qt * 64 + 32 + q) * DIM;
#pragma unroll
    for (int c = 0; c < 4; c++) {
        float4 o0, o1;
        o0.x = acc0[c*4+0]*li0; o0.y = acc0[c*4+1]*li0; o0.z = acc0[c*4+2]*li0; o0.w = acc0[c*4+3]*li0;
        o1.x = acc1[c*4+0]*li1; o1.y = acc1[c*4+1]*li1; o1.z = acc1[c*4+2]*li1; o1.w = acc1[c*4+3]*li1;
        *(float4*)&Ob0[(c * 8 + g) * 4] = o0;
        *(float4*)&Ob1[(c * 8 + g) * 4] = o1;
    }
}

extern "C" void kernel_launch(void* const* d_in, const int* in_sizes, int n_in,
                              void* d_out, int out_size, void* d_ws, size_t ws_size,
                              hipStream_t stream) {
    const float* Q = (const float*)d_in[0];
    const float* K = (const float*)d_in[1];
    const float* V = (const float*)d_in[2];
    float* out = (float*)d_out;
    float* ws = (float*)d_ws;
    float* G  = ws;                                   // unused (layout stability)
    float* S  = G + (size_t)BH * DIM * DIM;
    float* Bm = S + BH * DIM;
    float* Kp = Bm + (size_t)BH * DIM * RP;
    float* Qp = Kp + (size_t)BH * KLEN * RP;
    float* Gpart = Kp;                                // 4 * BH * 128 * 128 floats (pre-proj scratch)
    float* Spart = Gpart + (size_t)4 * BH * DIM * DIM;

    gram_kernel<<<dim3(4, BH), 256, 0, stream>>>(K, Gpart, Spart);
    jacobi_kernel<<<dim3(4, BH), 1024, 0, stream>>>(Gpart, Spart, Bm);
    proj_kernel<<<dim3(KLEN / 64, BH), 256, 0, stream>>>(K, Bm, Kp, KLEN);
    proj_kernel<<<dim3(QLEN / 64, BH), 256, 0, stream>>>(Q, Bm, Qp, QLEN);
    attn_kernel<<<dim3(QLEN / 64, BH), 256, 0, stream>>>(Qp, Kp, V, out);
}